// Round 1
// 12161.617 us; speedup vs baseline: 1.4510x; 1.4510x over previous
//
#include <hip/hip_runtime.h>
#include <stdint.h>

#define T_DIM 2048
#define B_DIM 64
#define IDIM_ 1024
#define HDIM_ 1024
#define ODIM_ 512

typedef short s8v __attribute__((ext_vector_type(8)));
typedef float f4v __attribute__((ext_vector_type(4)));

__device__ __forceinline__ float bf2f(unsigned short u) {
  union { unsigned int i; float f; } v; v.i = ((unsigned int)u) << 16; return v.f;
}
__device__ __forceinline__ unsigned short f2bf(float f) {
  union { float f; unsigned int i; } v; v.f = f;
  unsigned int u = v.i;
  return (unsigned short)((u + 0x7FFFu + ((u >> 16) & 1u)) >> 16);  // RNE, inputs finite
}
__device__ __forceinline__ unsigned int pack2(float lo, float hi) {
  return (unsigned int)f2bf(lo) | ((unsigned int)f2bf(hi) << 16);
}
__device__ __forceinline__ float fast_tanh(float x) {
  float cx = fminf(fmaxf(x, -9.f), 9.f);     // tanh saturates; avoids expf overflow
  float e = __expf(2.f * cx);
  return (e - 1.f) / (e + 1.f);
}

// ---------------------------------------------------------------- weights fp32 -> bf16
__global__ void cvt_weights(const float* __restrict__ wih, const float* __restrict__ whh,
                            unsigned short* __restrict__ wihb, unsigned short* __restrict__ whhb) {
  int idx = blockIdx.x * blockDim.x + threadIdx.x;
  int stride = gridDim.x * blockDim.x;
  const int n4 = (HDIM_ * IDIM_) / 4;
  for (int i = idx; i < n4; i += stride) {
    float4 a = ((const float4*)wih)[i];
    float4 b = ((const float4*)whh)[i];
    uint2 ra = { pack2(a.x, a.y), pack2(a.z, a.w) };
    uint2 rb = { pack2(b.x, b.y), pack2(b.z, b.w) };
    ((uint2*)wihb)[i] = ra;
    ((uint2*)whhb)[i] = rb;
  }
}

// ---------------------------------------------------------------- phase 1: A = X @ Wih^T + bh
__global__ __launch_bounds__(256) void xproj_gemm(
    const float* __restrict__ X, const unsigned short* __restrict__ Wb,
    const float* __restrict__ bh, unsigned short* __restrict__ A) {
  __shared__ unsigned short Xs[128][40];
  __shared__ unsigned short Wls[128][40];

  const int tid = threadIdx.x;
  const int bid = blockIdx.x;
  const int mt = bid >> 3, nt = bid & 7;
  const size_t mbase = (size_t)mt * 128;
  const int nbase = nt * 128;

  const int wave = tid >> 6, lane = tid & 63;
  const int row16 = lane & 15, quad = lane >> 4;
  const int wm = wave >> 1, wn = wave & 1;

  f4v acc[4][4];
#pragma unroll
  for (int i = 0; i < 4; ++i)
#pragma unroll
    for (int j = 0; j < 4; ++j) acc[i][j] = (f4v){0.f, 0.f, 0.f, 0.f};

  const int r_st = tid >> 1, half = tid & 1;

  for (int k0 = 0; k0 < IDIM_; k0 += 32) {
    {
      const float* src = X + (mbase + r_st) * IDIM_ + k0 + half * 16;
      float4 f0 = ((const float4*)src)[0];
      float4 f1 = ((const float4*)src)[1];
      float4 f2 = ((const float4*)src)[2];
      float4 f3 = ((const float4*)src)[3];
      uint4 w0 = { pack2(f0.x,f0.y), pack2(f0.z,f0.w), pack2(f1.x,f1.y), pack2(f1.z,f1.w) };
      uint4 w1 = { pack2(f2.x,f2.y), pack2(f2.z,f2.w), pack2(f3.x,f3.y), pack2(f3.z,f3.w) };
      *(uint4*)&Xs[r_st][half * 16] = w0;
      *(uint4*)&Xs[r_st][half * 16 + 8] = w1;
    }
    if (tid < 128) {
      const uint4* src = (const uint4*)(Wb + (size_t)(nbase + tid) * IDIM_ + k0);
      uint4 w0 = src[0], w1 = src[1], w2 = src[2], w3 = src[3];
      *(uint4*)&Wls[tid][0]  = w0;
      *(uint4*)&Wls[tid][8]  = w1;
      *(uint4*)&Wls[tid][16] = w2;
      *(uint4*)&Wls[tid][24] = w3;
    }
    __syncthreads();
    s8v a[4], b[4];
#pragma unroll
    for (int i = 0; i < 4; ++i) a[i] = *(const s8v*)&Xs[64 * wm + 16 * i + row16][quad * 8];
#pragma unroll
    for (int j = 0; j < 4; ++j) b[j] = *(const s8v*)&Wls[64 * wn + 16 * j + row16][quad * 8];
#pragma unroll
    for (int i = 0; i < 4; ++i)
#pragma unroll
      for (int j = 0; j < 4; ++j)
        acc[i][j] = __builtin_amdgcn_mfma_f32_16x16x32_bf16(a[i], b[j], acc[i][j], 0, 0, 0);
    __syncthreads();
  }
#pragma unroll
  for (int j = 0; j < 4; ++j) {
    int n = nbase + 64 * wn + 16 * j + row16;
    float bias = bh[n];
#pragma unroll
    for (int i = 0; i < 4; ++i) {
      size_t m0 = mbase + 64 * wm + 16 * i + quad * 4;
#pragma unroll
      for (int r = 0; r < 4; ++r)
        A[(m0 + r) * HDIM_ + n] = f2bf(acc[i][j][r] + bias);
    }
  }
}

// ---------------------------------------------------------------- phase 2: persistent recurrence
// 64 blocks x 256 threads; block g owns h cols [16g,16g+16).
// Sync: per-(block,wave) monotonic flags (sc-bypass). Data: h stores are
// sc-bypass write-through (reach MALL before flag; release = vmcnt(0)).
// h LOADS are explicit sc0+sc1 bypass loads (straight from MALL) -> NO per-step
// acquire fence / L2 invalidate. This removes the 8-blocks-per-XCD invalidate
// interference and the 128KB/step L2 refill storm (was ~1.6GB of FETCH).
// Ordering: bypass loads issue in-order after the poll's flag load completed
// (asm volatile + "memory" stops compiler hoisting); producer vmcnt(0) before
// flag covers both its stores and its step-t-1 reads (anti-dep unchanged).
__global__ __launch_bounds__(256, 1) void rnn_persist(
    const unsigned short* __restrict__ A,    // [64][2048][1024] bf16 (b,t,h)
    const unsigned short* __restrict__ Whh,  // [1024][1024] bf16
    const float* __restrict__ Wout,          // [512][1024] fp32
    const float* __restrict__ bout,          // [512]
    unsigned short* __restrict__ h0, unsigned short* __restrict__ h1,
    unsigned int* flags, float* __restrict__ out) {
  const int g = blockIdx.x;
  const int tid = threadIdx.x;
  const int wave = tid >> 6, lane = tid & 63;
  const int row16 = lane & 15, quad = lane >> 4;
  const int n0 = g * 16;

  // W_hh col-slice, MFMA B-frag layout: lane holds col=row16, k=quad*8+j
  s8v wreg[32];
  {
    const unsigned short* wrow = Whh + (size_t)(n0 + row16) * HDIM_ + quad * 8;
#pragma unroll
    for (int kk = 0; kk < 32; ++kk) wreg[kk] = *(const s8v*)(wrow + (size_t)kk * 32);
  }

  const int bb = 16 * wave + quad * 4;                       // my 4 output rows bb..bb+3
  unsigned int* myflag = flags + (g * 4 + wave) * 32;        // 128B-spaced slot
  const unsigned int* pollflag = flags + (lane * 4 + wave) * 32;  // producer block=lane, my wave
  const size_t abase = (size_t)bb * T_DIM * HDIM_ + n0 + row16;

  float aval[4];
#pragma unroll
  for (int r = 0; r < 4; ++r)
    aval[r] = bf2f(A[abase + (size_t)r * T_DIM * HDIM_]);    // col t=0

  for (int t = 0; t < T_DIM; ++t) {
    unsigned short* hn = (t & 1) ? h1 : h0;
    const unsigned short* hp = (t & 1) ? h0 : h1;

    f4v acc0 = (f4v){0.f, 0.f, 0.f, 0.f};
    f4v acc1 = (f4v){0.f, 0.f, 0.f, 0.f};
    if (t > 0) {
      // wait for wave-w slice of h_{t-1} from all 64 producer blocks
      while (__hip_atomic_load(pollflag, __ATOMIC_RELAXED, __HIP_MEMORY_SCOPE_AGENT) < (unsigned)t) {}
      const unsigned short* hbase = hp + (size_t)(16 * wave + row16) * HDIM_ + quad * 8;
      s8v hreg[32];
      // issue all 32 16B h loads, L1/L2-bypass (sc0 sc1): MALL-fresh, no fence.
      // One base address + 13-bit immediate offsets (kk*64B <= 1984).
#define HL(k) asm volatile("global_load_dwordx4 %0, %1, off offset:" #k " sc0 sc1" \
                           : "=v"(hreg[(k) / 64]) : "v"(hbase) : "memory")
      HL(0);    HL(64);   HL(128);  HL(192);  HL(256);  HL(320);  HL(384);  HL(448);
      HL(512);  HL(576);  HL(640);  HL(704);  HL(768);  HL(832);  HL(896);  HL(960);
      HL(1024); HL(1088); HL(1152); HL(1216); HL(1280); HL(1344); HL(1408); HL(1472);
      HL(1536); HL(1600); HL(1664); HL(1728); HL(1792); HL(1856); HL(1920); HL(1984);
#undef HL
      // counted-vmcnt pipeline: chunk c ready when <= (24-8c) newest remain.
      // Valid even with <=4 older A-prefetch loads outstanding (in-order retire).
#define CHUNK(c, n)                                                                  \
      asm volatile("s_waitcnt vmcnt(" #n ")" ::: "memory");                          \
      __builtin_amdgcn_sched_barrier(0);                                             \
      _Pragma("unroll")                                                              \
      for (int kk = 8 * (c); kk < 8 * (c) + 8; kk += 2) {                            \
        acc0 = __builtin_amdgcn_mfma_f32_16x16x32_bf16(hreg[kk], wreg[kk], acc0, 0, 0, 0);         \
        acc1 = __builtin_amdgcn_mfma_f32_16x16x32_bf16(hreg[kk + 1], wreg[kk + 1], acc1, 0, 0, 0); \
      }
      CHUNK(0, 24)
      CHUNK(1, 16)
      CHUNK(2, 8)
      CHUNK(3, 0)
#undef CHUNK
    }
#pragma unroll
    for (int r = 0; r < 4; ++r) {
      float v = fast_tanh(acc0[r] + acc1[r] + aval[r]);
      __hip_atomic_store(&hn[(size_t)(bb + r) * HDIM_ + n0 + row16], f2bf(v),
                         __ATOMIC_RELAXED, __HIP_MEMORY_SCOPE_AGENT);
    }
    asm volatile("s_waitcnt vmcnt(0)" ::: "memory");  // release: h stores at MALL
    if (lane == 0)
      __hip_atomic_store(myflag, (unsigned)(t + 1), __ATOMIC_RELAXED, __HIP_MEMORY_SCOPE_AGENT);
    // prefetch A col t+1 (plain cached loads, read-only) to overlap the next poll
    if (t + 1 < T_DIM) {
#pragma unroll
      for (int r = 0; r < 4; ++r)
        aval[r] = bf2f(A[abase + (size_t)r * T_DIM * HDIM_ + (size_t)(t + 1) * HDIM_]);
    }
  }

  // wait for ALL waves' final slices, then read h_2047 (in h1) with fresh caches
  {
    const unsigned int* fl = flags + tid * 32;
    while (__hip_atomic_load(fl, __ATOMIC_RELAXED, __HIP_MEMORY_SCOPE_AGENT) < (unsigned)T_DIM) {}
  }
  __syncthreads();
  __builtin_amdgcn_fence(__ATOMIC_ACQUIRE, "agent");  // one-time: epilogue uses cached loads

  for (int idx = tid; idx < B_DIM * 8; idx += 256) {
    int b = idx >> 3;
    int o = g * 8 + (idx & 7);
    const unsigned short* hr = h1 + (size_t)b * HDIM_;
    const float* wr = Wout + (size_t)o * HDIM_;
    float s = 0.f;
    for (int k = 0; k < HDIM_; k += 4) {
      float4 w = *(const float4*)(wr + k);
      s += bf2f(hr[k]) * w.x + bf2f(hr[k + 1]) * w.y + bf2f(hr[k + 2]) * w.z + bf2f(hr[k + 3]) * w.w;
    }
    out[b * ODIM_ + o] = s + bout[o];
  }
}

// ---------------------------------------------------------------- launch
extern "C" void kernel_launch(void* const* d_in, const int* in_sizes, int n_in,
                              void* d_out, int out_size, void* d_ws, size_t ws_size,
                              hipStream_t stream) {
  const float* x    = (const float*)d_in[0];
  const float* Wih  = (const float*)d_in[1];
  const float* Whh  = (const float*)d_in[2];
  const float* bh   = (const float*)d_in[3];
  const float* Wout = (const float*)d_in[4];
  const float* bout = (const float*)d_in[5];
  float* out = (float*)d_out;

  char* ws = (char*)d_ws;
  // layout: A 256MiB | WihB 2MiB | WhhB 2MiB | h0 128KiB | h1 128KiB | flags 32KiB
  unsigned short* A    = (unsigned short*)ws;
  unsigned short* WihB = (unsigned short*)(ws + (size_t)268435456);
  unsigned short* WhhB = (unsigned short*)(ws + (size_t)268435456 + 2097152);
  unsigned short* h0   = (unsigned short*)(ws + (size_t)268435456 + 2 * 2097152);
  unsigned short* h1   = h0 + 65536;
  unsigned int*   flags = (unsigned int*)(h1 + 65536);

  hipMemsetAsync(flags, 0, 256 * 128, stream);
  cvt_weights<<<256, 256, 0, stream>>>(Wih, Whh, WihB, WhhB);
  xproj_gemm<<<8192, 256, 0, stream>>>(x, WihB, bh, A);
  rnn_persist<<<64, 256, 0, stream>>>(A, WhhB, Wout, bout, h0, h1, flags, out);
}

// Round 2
// 12121.172 us; speedup vs baseline: 1.4558x; 1.0033x over previous
//
#include <hip/hip_runtime.h>
#include <stdint.h>

#define T_DIM 2048
#define B_DIM 64
#define IDIM_ 1024
#define HDIM_ 1024
#define ODIM_ 512

typedef short s8v __attribute__((ext_vector_type(8)));
typedef float f4v __attribute__((ext_vector_type(4)));

__device__ __forceinline__ float bf2f(unsigned short u) {
  union { unsigned int i; float f; } v; v.i = ((unsigned int)u) << 16; return v.f;
}
__device__ __forceinline__ unsigned short f2bf(float f) {
  union { float f; unsigned int i; } v; v.f = f;
  unsigned int u = v.i;
  return (unsigned short)((u + 0x7FFFu + ((u >> 16) & 1u)) >> 16);  // RNE, inputs finite
}
__device__ __forceinline__ unsigned int pack2(float lo, float hi) {
  return (unsigned int)f2bf(lo) | ((unsigned int)f2bf(hi) << 16);
}
__device__ __forceinline__ float fast_tanh(float x) {
  float cx = fminf(fmaxf(x, -9.f), 9.f);     // tanh saturates; avoids expf overflow
  float e = __expf(2.f * cx);
  return (e - 1.f) / (e + 1.f);
}

// ---------------------------------------------------------------- weights fp32 -> bf16
__global__ void cvt_weights(const float* __restrict__ wih, const float* __restrict__ whh,
                            unsigned short* __restrict__ wihb, unsigned short* __restrict__ whhb) {
  int idx = blockIdx.x * blockDim.x + threadIdx.x;
  int stride = gridDim.x * blockDim.x;
  const int n4 = (HDIM_ * IDIM_) / 4;
  for (int i = idx; i < n4; i += stride) {
    float4 a = ((const float4*)wih)[i];
    float4 b = ((const float4*)whh)[i];
    uint2 ra = { pack2(a.x, a.y), pack2(a.z, a.w) };
    uint2 rb = { pack2(b.x, b.y), pack2(b.z, b.w) };
    ((uint2*)wihb)[i] = ra;
    ((uint2*)whhb)[i] = rb;
  }
}

// ---------------------------------------------------------------- phase 1: A = X @ Wih^T + bh
__global__ __launch_bounds__(256) void xproj_gemm(
    const float* __restrict__ X, const unsigned short* __restrict__ Wb,
    const float* __restrict__ bh, unsigned short* __restrict__ A) {
  __shared__ unsigned short Xs[128][40];
  __shared__ unsigned short Wls[128][40];

  const int tid = threadIdx.x;
  const int bid = blockIdx.x;
  const int mt = bid >> 3, nt = bid & 7;
  const size_t mbase = (size_t)mt * 128;
  const int nbase = nt * 128;

  const int wave = tid >> 6, lane = tid & 63;
  const int row16 = lane & 15, quad = lane >> 4;
  const int wm = wave >> 1, wn = wave & 1;

  f4v acc[4][4];
#pragma unroll
  for (int i = 0; i < 4; ++i)
#pragma unroll
    for (int j = 0; j < 4; ++j) acc[i][j] = (f4v){0.f, 0.f, 0.f, 0.f};

  const int r_st = tid >> 1, half = tid & 1;

  for (int k0 = 0; k0 < IDIM_; k0 += 32) {
    {
      const float* src = X + (mbase + r_st) * IDIM_ + k0 + half * 16;
      float4 f0 = ((const float4*)src)[0];
      float4 f1 = ((const float4*)src)[1];
      float4 f2 = ((const float4*)src)[2];
      float4 f3 = ((const float4*)src)[3];
      uint4 w0 = { pack2(f0.x,f0.y), pack2(f0.z,f0.w), pack2(f1.x,f1.y), pack2(f1.z,f1.w) };
      uint4 w1 = { pack2(f2.x,f2.y), pack2(f2.z,f2.w), pack2(f3.x,f3.y), pack2(f3.z,f3.w) };
      *(uint4*)&Xs[r_st][half * 16] = w0;
      *(uint4*)&Xs[r_st][half * 16 + 8] = w1;
    }
    if (tid < 128) {
      const uint4* src = (const uint4*)(Wb + (size_t)(nbase + tid) * IDIM_ + k0);
      uint4 w0 = src[0], w1 = src[1], w2 = src[2], w3 = src[3];
      *(uint4*)&Wls[tid][0]  = w0;
      *(uint4*)&Wls[tid][8]  = w1;
      *(uint4*)&Wls[tid][16] = w2;
      *(uint4*)&Wls[tid][24] = w3;
    }
    __syncthreads();
    s8v a[4], b[4];
#pragma unroll
    for (int i = 0; i < 4; ++i) a[i] = *(const s8v*)&Xs[64 * wm + 16 * i + row16][quad * 8];
#pragma unroll
    for (int j = 0; j < 4; ++j) b[j] = *(const s8v*)&Wls[64 * wn + 16 * j + row16][quad * 8];
#pragma unroll
    for (int i = 0; i < 4; ++i)
#pragma unroll
      for (int j = 0; j < 4; ++j)
        acc[i][j] = __builtin_amdgcn_mfma_f32_16x16x32_bf16(a[i], b[j], acc[i][j], 0, 0, 0);
    __syncthreads();
  }
#pragma unroll
  for (int j = 0; j < 4; ++j) {
    int n = nbase + 64 * wn + 16 * j + row16;
    float bias = bh[n];
#pragma unroll
    for (int i = 0; i < 4; ++i) {
      size_t m0 = mbase + 64 * wm + 16 * i + quad * 4;
#pragma unroll
      for (int r = 0; r < 4; ++r)
        A[(m0 + r) * HDIM_ + n] = f2bf(acc[i][j][r] + bias);
    }
  }
}

// ---------------------------------------------------------------- phase 2: persistent recurrence
// 64 blocks x 256 threads; block g owns h cols [16g,16g+16).
// Sync: per-(block,wave) monotonic flags (sc-bypass). Producer h stores are
// sc-bypass write-through (reach MALL before flag; release = vmcnt(0)).
// h READS are PLAIN CACHED loads from a ROTATING buffer (64 slots x 128KB):
// each step's h lands at a fresh address, so the consumer's L2 miss pulls the
// MALL-fresh data and the other 7 blocks on that XCD hit L2 (automatic
// XCD-level broadcast; placement only affects hit rate, never correctness).
// This cuts the 8MB/step of fine-grained sc0sc1 MALL reads to ~1MB/step of
// line fills. Staleness across the 64-step rotation: one acquire fence
// (buffer_inv) every 64 steps; cross-dispatch staleness: kernel-boundary inv.
__global__ __launch_bounds__(256, 1) void rnn_persist(
    const unsigned short* __restrict__ A,    // [64][2048][1024] bf16 (b,t,h)
    const unsigned short* __restrict__ Whh,  // [1024][1024] bf16
    const float* __restrict__ Wout,          // [512][1024] fp32
    const float* __restrict__ bout,          // [512]
    unsigned short* __restrict__ hrot,       // 64 slots x [64][1024] bf16
    unsigned int* flags, float* __restrict__ out) {
  const int g = blockIdx.x;
  const int tid = threadIdx.x;
  const int wave = tid >> 6, lane = tid & 63;
  const int row16 = lane & 15, quad = lane >> 4;
  const int n0 = g * 16;

  // W_hh col-slice, MFMA B-frag layout: lane holds col=row16, k=quad*8+j
  s8v wreg[32];
  {
    const unsigned short* wrow = Whh + (size_t)(n0 + row16) * HDIM_ + quad * 8;
#pragma unroll
    for (int kk = 0; kk < 32; ++kk) wreg[kk] = *(const s8v*)(wrow + (size_t)kk * 32);
  }

  const int bb = 16 * wave + quad * 4;                       // my 4 output rows bb..bb+3
  unsigned int* myflag = flags + (g * 4 + wave) * 32;        // 128B-spaced slot
  const unsigned int* pollflag = flags + (lane * 4 + wave) * 32;  // producer block=lane, my wave
  const size_t abase = (size_t)bb * T_DIM * HDIM_ + n0 + row16;

  float aval[4];
#pragma unroll
  for (int r = 0; r < 4; ++r)
    aval[r] = bf2f(A[abase + (size_t)r * T_DIM * HDIM_]);    // col t=0

  for (int t = 0; t < T_DIM; ++t) {
    unsigned short* hn = hrot + (size_t)(t & 63) * 65536;          // slot for h_t
    const unsigned short* hp = hrot + (size_t)((t - 1) & 63) * 65536;  // slot of h_{t-1}

    f4v acc0 = (f4v){0.f, 0.f, 0.f, 0.f};
    f4v acc1 = (f4v){0.f, 0.f, 0.f, 0.f};
    if (t > 0) {
      // wait for wave-w slice of h_{t-1} from all 64 producer blocks
      while (__hip_atomic_load(pollflag, __ATOMIC_RELAXED, __HIP_MEMORY_SCOPE_AGENT) < (unsigned)t) {}
      // rotation-epoch boundary: drop lines cached 64 steps ago so this
      // epoch's slot reads miss to MALL-fresh data. Amortized 1/64 steps.
      if ((t & 63) == 0)
        __builtin_amdgcn_fence(__ATOMIC_ACQUIRE, "agent");
      const unsigned short* hbase = hp + (size_t)(16 * wave + row16) * HDIM_ + quad * 8;
      s8v hreg[32];
      // issue all 32 16B h loads, PLAIN CACHED (L1/L2 allocate): slot address
      // is fresh this epoch -> miss pulls MALL-written data; same-XCD blocks
      // share the fill via L2. One base address + 13-bit immediate offsets.
#define HL(k) asm volatile("global_load_dwordx4 %0, %1, off offset:" #k \
                           : "=v"(hreg[(k) / 64]) : "v"(hbase) : "memory")
      HL(0);    HL(64);   HL(128);  HL(192);  HL(256);  HL(320);  HL(384);  HL(448);
      HL(512);  HL(576);  HL(640);  HL(704);  HL(768);  HL(832);  HL(896);  HL(960);
      HL(1024); HL(1088); HL(1152); HL(1216); HL(1280); HL(1344); HL(1408); HL(1472);
      HL(1536); HL(1600); HL(1664); HL(1728); HL(1792); HL(1856); HL(1920); HL(1984);
#undef HL
      // counted-vmcnt pipeline: chunk c ready when <= (24-8c) newest remain.
#define CHUNK(c, n)                                                                  \
      asm volatile("s_waitcnt vmcnt(" #n ")" ::: "memory");                          \
      __builtin_amdgcn_sched_barrier(0);                                             \
      _Pragma("unroll")                                                              \
      for (int kk = 8 * (c); kk < 8 * (c) + 8; kk += 2) {                            \
        acc0 = __builtin_amdgcn_mfma_f32_16x16x32_bf16(hreg[kk], wreg[kk], acc0, 0, 0, 0);         \
        acc1 = __builtin_amdgcn_mfma_f32_16x16x32_bf16(hreg[kk + 1], wreg[kk + 1], acc1, 0, 0, 0); \
      }
      CHUNK(0, 24)
      CHUNK(1, 16)
      CHUNK(2, 8)
      CHUNK(3, 0)
#undef CHUNK
    }
#pragma unroll
    for (int r = 0; r < 4; ++r) {
      float v = fast_tanh(acc0[r] + acc1[r] + aval[r]);
      __hip_atomic_store(&hn[(size_t)(bb + r) * HDIM_ + n0 + row16], f2bf(v),
                         __ATOMIC_RELAXED, __HIP_MEMORY_SCOPE_AGENT);
    }
    asm volatile("s_waitcnt vmcnt(0)" ::: "memory");  // release: h stores at MALL
    if (lane == 0)
      __hip_atomic_store(myflag, (unsigned)(t + 1), __ATOMIC_RELAXED, __HIP_MEMORY_SCOPE_AGENT);
    // prefetch A col t+1 (plain cached loads, read-only) to overlap the next poll
    if (t + 1 < T_DIM) {
#pragma unroll
      for (int r = 0; r < 4; ++r)
        aval[r] = bf2f(A[abase + (size_t)r * T_DIM * HDIM_ + (size_t)(t + 1) * HDIM_]);
    }
  }

  // wait for ALL waves' final slices, then read h_2047 (slot 2047&63 = 63)
  {
    const unsigned int* fl = flags + tid * 32;
    while (__hip_atomic_load(fl, __ATOMIC_RELAXED, __HIP_MEMORY_SCOPE_AGENT) < (unsigned)T_DIM) {}
  }
  __syncthreads();
  __builtin_amdgcn_fence(__ATOMIC_ACQUIRE, "agent");  // one-time: epilogue uses cached loads

  const unsigned short* hlast = hrot + (size_t)63 * 65536;
  for (int idx = tid; idx < B_DIM * 8; idx += 256) {
    int b = idx >> 3;
    int o = g * 8 + (idx & 7);
    const unsigned short* hr = hlast + (size_t)b * HDIM_;
    const float* wr = Wout + (size_t)o * HDIM_;
    float s = 0.f;
    for (int k = 0; k < HDIM_; k += 4) {
      float4 w = *(const float4*)(wr + k);
      s += bf2f(hr[k]) * w.x + bf2f(hr[k + 1]) * w.y + bf2f(hr[k + 2]) * w.z + bf2f(hr[k + 3]) * w.w;
    }
    out[b * ODIM_ + o] = s + bout[o];
  }
}

// ---------------------------------------------------------------- launch
extern "C" void kernel_launch(void* const* d_in, const int* in_sizes, int n_in,
                              void* d_out, int out_size, void* d_ws, size_t ws_size,
                              hipStream_t stream) {
  const float* x    = (const float*)d_in[0];
  const float* Wih  = (const float*)d_in[1];
  const float* Whh  = (const float*)d_in[2];
  const float* bh   = (const float*)d_in[3];
  const float* Wout = (const float*)d_in[4];
  const float* bout = (const float*)d_in[5];
  float* out = (float*)d_out;

  char* ws = (char*)d_ws;
  // layout: A 256MiB | WihB 2MiB | WhhB 2MiB | hrot 8MiB (64 slots) | flags 32KiB
  unsigned short* A    = (unsigned short*)ws;
  unsigned short* WihB = (unsigned short*)(ws + (size_t)268435456);
  unsigned short* WhhB = (unsigned short*)(ws + (size_t)268435456 + 2097152);
  unsigned short* hrot = (unsigned short*)(ws + (size_t)268435456 + 2 * 2097152);
  unsigned int*   flags = (unsigned int*)(ws + (size_t)268435456 + 2 * 2097152 + 8388608);

  hipMemsetAsync(flags, 0, 256 * 128, stream);
  cvt_weights<<<256, 256, 0, stream>>>(Wih, Whh, WihB, WhhB);
  xproj_gemm<<<8192, 256, 0, stream>>>(x, WihB, bh, A);
  rnn_persist<<<64, 256, 0, stream>>>(A, WhhB, Wout, bout, hrot, flags, out);
}